// Round 2
// baseline (86.282 us; speedup 1.0000x reference)
//
#include <hip/hip_runtime.h>

// Bilateral filter 3x3, sigma_color == sigma_space == 0.8, reflect-101 pad.
// Key simplifications (mathematically exact vs reference):
//  - color-weight normalization cancels between numerator and denominator
//  - spatial-kernel normalization cancels identically
//  - sigma_color == sigma_space => spatial+color weights fuse into ONE exp2:
//      w = exp2(-(di^2+dj^2 + diff^2) * 0.78125 * log2(e))
#define HW 512

__global__ __launch_bounds__(256) void bilateral3x3(const float* __restrict__ in,
                                                    float* __restrict__ out,
                                                    int ngroups) {
    int gid = blockIdx.x * 256 + threadIdx.x;   // one thread = 4 pixels along x
    if (gid >= ngroups) return;

    int xg    = gid & 127;          // 128 groups of 4 per row
    int y     = (gid >> 7) & 511;
    int plane = gid >> 16;          // b*c plane (24 planes)

    const float* p = in + (size_t)plane * (HW * HW);
    int x0 = xg << 2;

    // reflect-101: -1 -> 1, 512 -> 510
    int ym = (y == 0)   ? 1   : y - 1;
    int yp = (y == 511) ? 510 : y + 1;
    int xl = (x0 == 0)   ? 1   : x0 - 1;
    int xr = (x0 == 508) ? 510 : x0 + 4;

    const float* rp0 = p + (size_t)ym * HW;
    const float* rp1 = p + (size_t)y  * HW;
    const float* rp2 = p + (size_t)yp * HW;

    float r[3][6];
    {
        float4 c4;
        c4 = *reinterpret_cast<const float4*>(rp0 + x0);
        r[0][0] = rp0[xl]; r[0][1] = c4.x; r[0][2] = c4.y; r[0][3] = c4.z; r[0][4] = c4.w; r[0][5] = rp0[xr];
        c4 = *reinterpret_cast<const float4*>(rp1 + x0);
        r[1][0] = rp1[xl]; r[1][1] = c4.x; r[1][2] = c4.y; r[1][3] = c4.z; r[1][4] = c4.w; r[1][5] = rp1[xr];
        c4 = *reinterpret_cast<const float4*>(rp2 + x0);
        r[2][0] = rp2[xl]; r[2][1] = c4.x; r[2][2] = c4.y; r[2][3] = c4.z; r[2][4] = c4.w; r[2][5] = rp2[xr];
    }

    const float C = 1.1271055f;     // 0.78125 * log2(e);  0.78125 = 1/(2*0.8^2)
    float res[4];
    #pragma unroll
    for (int j = 0; j < 4; ++j) {
        float c = r[1][j + 1];
        float num = 0.f, den = 0.f;
        #pragma unroll
        for (int dy = 0; dy < 3; ++dy) {
            #pragma unroll
            for (int dx = 0; dx < 3; ++dx) {
                float pv = r[dy][j + dx];
                float d  = pv - c;
                float sp = (float)((dy - 1) * (dy - 1) + (dx - 1) * (dx - 1));
                float w  = exp2f(-(sp + d * d) * C);   // native v_exp_f32
                num = fmaf(w, pv, num);
                den += w;
            }
        }
        res[j] = __fdividef(num, den);
    }

    float4 o;
    o.x = res[0]; o.y = res[1]; o.z = res[2]; o.w = res[3];
    *reinterpret_cast<float4*>(out + (size_t)plane * (HW * HW) + (size_t)y * HW + x0) = o;
}

extern "C" void kernel_launch(void* const* d_in, const int* in_sizes, int n_in,
                              void* d_out, int out_size, void* d_ws, size_t ws_size,
                              hipStream_t stream) {
    const float* in = (const float*)d_in[0];
    float* out = (float*)d_out;
    int total = in_sizes[0];            // 8*3*512*512
    int ngroups = total >> 2;           // 4 pixels per thread
    int blocks = (ngroups + 255) / 256;
    bilateral3x3<<<blocks, 256, 0, stream>>>(in, out, ngroups);
}

// Round 3
// 81.569 us; speedup vs baseline: 1.0578x; 1.0578x over previous
//
#include <hip/hip_runtime.h>

// Bilateral filter 3x3, sigma_color == sigma_space == 0.8, reflect-101 pad.
// Exact algebraic simplifications vs reference:
//  - color-weight and spatial-kernel normalizations cancel num/den
//  - sigma_color == sigma_space => one fused exp2 per tap:
//      w = exp2(-(di^2+dj^2 + diff^2) * (1/(2*0.8^2)) * log2(e))
//  - center tap always has w == 1 (d=0, sp=0): folded into accumulator init
// Raw __builtin_amdgcn_exp2f / rcpf: arg in [-3.4, 0], den in [0.86, 9] — safe,
// avoids OCML's denormal-scaling wrapper (~5 extra VALU per tap).
#define HW 512

__global__ __launch_bounds__(256) void bilateral3x3(const float* __restrict__ in,
                                                    float* __restrict__ out,
                                                    int nthreads) {
    int gid = blockIdx.x * 256 + threadIdx.x;   // one thread = 8 pixels along x
    if (gid >= nthreads) return;

    int xg    = gid & 63;           // 64 groups of 8 per row
    int y     = (gid >> 6) & 511;
    int plane = gid >> 15;          // b*c plane (24 planes)

    const float* p = in + (size_t)plane * (HW * HW);
    int x0 = xg << 3;

    // reflect-101: -1 -> 1, 512 -> 510
    int ym = (y == 0)   ? 1   : y - 1;
    int yp = (y == 511) ? 510 : y + 1;
    int xl = (x0 == 0)   ? 1   : x0 - 1;
    int xr = (x0 == 504) ? 510 : x0 + 8;

    const float* rp0 = p + (size_t)ym * HW;
    const float* rp1 = p + (size_t)y  * HW;
    const float* rp2 = p + (size_t)yp * HW;

    float v[3][10];
    #pragma unroll
    for (int i = 0; i < 3; ++i) {
        const float* rp = (i == 0) ? rp0 : (i == 1) ? rp1 : rp2;
        float4 a = *reinterpret_cast<const float4*>(rp + x0);
        float4 b = *reinterpret_cast<const float4*>(rp + x0 + 4);
        v[i][0] = rp[xl];
        v[i][1] = a.x; v[i][2] = a.y; v[i][3] = a.z; v[i][4] = a.w;
        v[i][5] = b.x; v[i][6] = b.y; v[i][7] = b.z; v[i][8] = b.w;
        v[i][9] = rp[xr];
    }

    const float nC = -1.1271055f;   // -(1/(2*0.8^2)) * log2(e)
    float res[8];
    #pragma unroll
    for (int j = 0; j < 8; ++j) {
        float c = v[1][j + 1];
        float num = c;              // center tap: w == 1
        float den = 1.0f;
        #pragma unroll
        for (int dy = 0; dy < 3; ++dy) {
            #pragma unroll
            for (int dx = 0; dx < 3; ++dx) {
                if (dy == 1 && dx == 1) continue;
                float pv = v[dy][j + dx];
                float d  = pv - c;
                float sp = (float)((dy - 1) * (dy - 1) + (dx - 1) * (dx - 1));
                float w  = __builtin_amdgcn_exp2f(fmaf(d, d, sp) * nC);
                num = fmaf(w, pv, num);
                den += w;
            }
        }
        res[j] = num * __builtin_amdgcn_rcpf(den);
    }

    float* op = out + (size_t)plane * (HW * HW) + (size_t)y * HW + x0;
    float4 o0 = {res[0], res[1], res[2], res[3]};
    float4 o1 = {res[4], res[5], res[6], res[7]};
    *reinterpret_cast<float4*>(op)     = o0;
    *reinterpret_cast<float4*>(op + 4) = o1;
}

extern "C" void kernel_launch(void* const* d_in, const int* in_sizes, int n_in,
                              void* d_out, int out_size, void* d_ws, size_t ws_size,
                              hipStream_t stream) {
    const float* in = (const float*)d_in[0];
    float* out = (float*)d_out;
    int total = in_sizes[0];            // 8*3*512*512
    int nthreads = total >> 3;          // 8 pixels per thread
    int blocks = (nthreads + 255) / 256;
    bilateral3x3<<<blocks, 256, 0, stream>>>(in, out, nthreads);
}

// Round 8
// 79.570 us; speedup vs baseline: 1.0844x; 1.0251x over previous
//
#include <hip/hip_runtime.h>

// Bilateral 3x3, sigma_color == sigma_space == 0.8, reflect-101.
// Exact simplifications: normalizations cancel; fused single exp2 per tap;
// center tap folded (w==1). Raw v_exp_f32 / v_rcp_f32 (args safely ranged).
// 2 output rows per thread via rolling 3-row register window
// (row loads per output row 3.0 -> 2.0), nontemporal output stores.
#define HW 512

typedef float vfloat4 __attribute__((ext_vector_type(4)));  // clang vector: OK for nontemporal builtin

__global__ __launch_bounds__(256) void bilateral3x3(const float* __restrict__ in,
                                                    float* __restrict__ out,
                                                    int nthreads) {
    int gid = blockIdx.x * 256 + threadIdx.x;   // one thread = 8 px wide x 2 rows
    if (gid >= nthreads) return;

    int xg    = gid & 63;           // 64 groups of 8 px per row
    int yg    = (gid >> 6) & 255;   // 256 row-pairs
    int plane = gid >> 14;          // 24 planes

    const float* p = in + (size_t)plane * (HW * HW);
    int x0 = xg << 3;
    int y0 = yg << 1;

    // reflect-101
    int ym = (y0 == 0)   ? 1   : y0 - 1;
    int yb = (y0 == 510) ? 510 : y0 + 2;
    int xl = (x0 == 0)   ? 1   : x0 - 1;
    int xr = (x0 == 504) ? 510 : x0 + 8;

    float A[10], B[10], C[10];
    auto loadrow = [&](float* w, int r) {
        const float* rp = p + (size_t)r * HW;
        vfloat4 a = *reinterpret_cast<const vfloat4*>(rp + x0);
        vfloat4 b = *reinterpret_cast<const vfloat4*>(rp + x0 + 4);
        w[0] = rp[xl];
        w[1] = a.x; w[2] = a.y; w[3] = a.z; w[4] = a.w;
        w[5] = b.x; w[6] = b.y; w[7] = b.z; w[8] = b.w;
        w[9] = rp[xr];
    };

    const float nC = -1.1271055f;   // -(1/(2*0.8^2)) * log2(e)

    auto dorow = [&](const float* T, const float* M, const float* Bo, float* op) {
        float res[8];
        #pragma unroll
        for (int j = 0; j < 8; ++j) {
            float c = M[j + 1];
            float num = c;          // center tap: w == 1
            float den = 1.0f;
            #pragma unroll
            for (int dx = 0; dx < 3; ++dx) {
                float spd = (float)(1 + (dx - 1) * (dx - 1));
                {   // top row
                    float pv = T[j + dx];
                    float d  = pv - c;
                    float w  = __builtin_amdgcn_exp2f(fmaf(d, d, spd) * nC);
                    num = fmaf(w, pv, num); den += w;
                }
                {   // bottom row
                    float pv = Bo[j + dx];
                    float d  = pv - c;
                    float w  = __builtin_amdgcn_exp2f(fmaf(d, d, spd) * nC);
                    num = fmaf(w, pv, num); den += w;
                }
                if (dx != 1) {  // middle row, center skipped
                    float pv = M[j + dx];
                    float d  = pv - c;
                    float w  = __builtin_amdgcn_exp2f(fmaf(d, d, 1.0f) * nC);
                    num = fmaf(w, pv, num); den += w;
                }
            }
            res[j] = num * __builtin_amdgcn_rcpf(den);
        }
        vfloat4 o0 = {res[0], res[1], res[2], res[3]};
        vfloat4 o1 = {res[4], res[5], res[6], res[7]};
        __builtin_nontemporal_store(o0, reinterpret_cast<vfloat4*>(op));
        __builtin_nontemporal_store(o1, reinterpret_cast<vfloat4*>(op) + 1);
    };

    float* outp = out + (size_t)plane * (HW * HW) + (size_t)y0 * HW + x0;

    loadrow(A, ym);         // row y0-1 (reflected)
    loadrow(B, y0);         // row y0
    loadrow(C, y0 + 1);     // row y0+1
    dorow(A, B, C, outp);   // out row y0
    loadrow(A, yb);         // row y0+2 (reflected) overwrites top buffer
    dorow(B, C, A, outp + HW);  // out row y0+1
}

extern "C" void kernel_launch(void* const* d_in, const int* in_sizes, int n_in,
                              void* d_out, int out_size, void* d_ws, size_t ws_size,
                              hipStream_t stream) {
    const float* in = (const float*)d_in[0];
    float* out = (float*)d_out;
    int total = in_sizes[0];            // 8*3*512*512
    int nthreads = total >> 4;          // 8 px x 2 rows per thread
    int blocks = (nthreads + 255) / 256;
    bilateral3x3<<<blocks, 256, 0, stream>>>(in, out, nthreads);
}